// Round 8
// baseline (1056.699 us; speedup 1.0000x reference)
//
#include <hip/hip_runtime.h>
#include <stdint.h>

typedef unsigned short u16;
typedef short bf16x8 __attribute__((ext_vector_type(8)));
typedef float f32x4 __attribute__((ext_vector_type(4)));

#define NTOK 4096
#define CDIM 512
#define NHEAD 8
#define LAYERS 8
#define MLPD 2048
#define QKVD 1536

__device__ __forceinline__ u16 f2bf(float f){
  union { float f; unsigned u; } c; c.f = f;
  return (u16)((c.u + 0x7FFFu + ((c.u >> 16) & 1u)) >> 16);
}

__device__ __forceinline__ unsigned pack2(float a, float b){
  return (unsigned)f2bf(a) | ((unsigned)f2bf(b) << 16);
}

__device__ __forceinline__ void llds16(const void* g, void* l){
  __builtin_amdgcn_global_load_lds((const __attribute__((address_space(1))) void*)g,
                                   (__attribute__((address_space(3))) void*)l, 16, 0, 0);
}

template<int N> __device__ __forceinline__ void wait_vmcnt(){
  if constexpr (N == 0) asm volatile("s_waitcnt vmcnt(0)" ::: "memory");
  else if constexpr (N == 2) asm volatile("s_waitcnt vmcnt(2)" ::: "memory");
  else if constexpr (N == 4) asm volatile("s_waitcnt vmcnt(4)" ::: "memory");
  else static_assert(N == 0 || N == 2 || N == 4, "unsupported vmcnt");
}

// ---------------- weight transpose+convert: W[K][N] fp32 -> Wt[N][K] bf16 ----------------
__global__ void kt_transpose(const float* __restrict__ W, u16* __restrict__ Wt, int K, int N){
  __shared__ float tile[32][33];
  int l = blockIdx.z;
  W  += (size_t)l * K * N;
  Wt += (size_t)l * K * N;
  int k0 = blockIdx.y * 32, n0 = blockIdx.x * 32;
  int t = threadIdx.x;
  int r = t >> 3, c4 = (t & 7) << 2;
  float4 v = *(const float4*)&W[(size_t)(k0 + r) * N + n0 + c4];
  tile[r][c4 + 0] = v.x; tile[r][c4 + 1] = v.y; tile[r][c4 + 2] = v.z; tile[r][c4 + 3] = v.w;
  __syncthreads();
  ushort4 o;
  o.x = f2bf(tile[c4 + 0][r]);
  o.y = f2bf(tile[c4 + 1][r]);
  o.z = f2bf(tile[c4 + 2][r]);
  o.w = f2bf(tile[c4 + 3][r]);
  *(ushort4*)&Wt[(size_t)(n0 + r) * K + k0 + c4] = o;
}

// ---------------- embed: h = feats@w_in + b_in + pos-emb ----------------
__global__ void kt_embed(const float* __restrict__ feats, const int* __restrict__ coords,
                         const float* __restrict__ ex, const float* __restrict__ ey,
                         const float* __restrict__ ez, const float* __restrict__ w_in,
                         const float* __restrict__ b_in, float* __restrict__ h){
  __shared__ float fs[8];
  __shared__ int cc[3];
  int n = blockIdx.x, t = threadIdx.x;
  if (t < 8) fs[t] = feats[n * 8 + t];
  if (t == 8) { cc[0] = coords[n*4+1]; cc[1] = coords[n*4+2]; cc[2] = coords[n*4+3]; }
  __syncthreads();
  for (int c = t; c < CDIM; c += 256){
    float acc = b_in[c];
    #pragma unroll
    for (int i = 0; i < 8; i++) acc += fs[i] * w_in[i * CDIM + c];
    float pe;
    if (c < 170)      pe = ex[cc[0] * 170 + c];
    else if (c < 340) pe = ey[cc[1] * 170 + (c - 170)];
    else              pe = ez[cc[2] * 172 + (c - 340)];
    h[(size_t)n * CDIM + c] = acc + pe;
  }
}

// ---------------- bf16 GEMM (optionally with fused input LayerNorm on A) ----------------
// C[M=4096][N] = LN?(A)[M][K] @ Wt[N][K]^T + bias
// 2-buffer, one __syncthreads per K-step. 4 waves; wave tile (BM/2)x(BN/2).
// XCD-chunked 1D grid swizzle (blocks on one XCD share A-panels; fits 4MB L2).
// LNA: A is fp32 h; per-block row stats (mean/rstd, eps 1e-6) computed once;
//      staging = reg-load f32 -> normalize*g+b -> swizzled ds_write_b128.
// MODE 0: qkv (Q/K -> outb bf16, V -> vT transposed bf16)
// MODE 1: hres += acc + bias  (fp32 residual)
// MODE 2: outb = bf16(gelu(acc + bias))
template<int BM, int BN, int MODE, bool LNA>
__global__ __launch_bounds__(256) void kt_gemm(
    const u16* __restrict__ A, const float* __restrict__ hA,
    const float* __restrict__ lng, const float* __restrict__ lnb,
    const u16* __restrict__ Wt, const float* __restrict__ bias,
    u16* __restrict__ outb, float* __restrict__ hres, u16* __restrict__ vT, int N, int K)
{
  constexpr int MF = BM / 32;
  constexpr int NF = BN / 32;
  constexpr int Mt = NTOK / BM;
  constexpr int Mx = Mt / 8;
  __shared__ __align__(16) u16 As[2][BM * 64];
  __shared__ __align__(16) u16 Bs[2][BN * 64];
  __shared__ float Gs[LNA ? CDIM : 1];
  __shared__ float Bt[LNA ? CDIM : 1];
  __shared__ float Mu[LNA ? BM : 1];
  __shared__ float Rs[LNA ? BM : 1];

  int tid = threadIdx.x, wave = tid >> 6, lane = tid & 63;

  int Nt = N / BN;
  int bid = blockIdx.x;
  int xcd = bid & 7, slot = bid >> 3;
  int miL = slot / Nt;
  int ni = slot - miL * Nt;
  int m0 = (xcd * Mx + miL) * BM, n0 = ni * BN;

  int wm = wave >> 1, wn = wave & 1;
  f32x4 acc[MF][NF];
  const f32x4 fzero = {0.f, 0.f, 0.f, 0.f};
  #pragma unroll
  for (int m = 0; m < MF; m++)
    #pragma unroll
    for (int n = 0; n < NF; n++) acc[m][n] = fzero;

  int srow = lane >> 3;
  int sblk = (lane & 7) ^ srow;
  const u16* gA = A  + (size_t)(m0 + wave * 8 + srow) * K + sblk * 8;
  const u16* gB = Wt + (size_t)(n0 + wave * 8 + srow) * K + sblk * 8;

  auto stageB = [&](int buf, int kt){
    #pragma unroll
    for (int j = 0; j < NF; j++)
      llds16(gB + (size_t)(j * 32) * K + kt, &Bs[buf][(j * 32 + wave * 8) * 64]);
  };
  auto stageA = [&](int buf, int kt){
    #pragma unroll
    for (int j = 0; j < MF; j++)
      llds16(gA + (size_t)(j * 32) * K + kt, &As[buf][(j * 32 + wave * 8) * 64]);
  };

  int r8 = tid >> 3, cb = tid & 7;     // LNA staging coords: row slot, logical col block
  float mu_[MF], rs_[MF];

  if constexpr (LNA){
    // gamma/beta -> LDS
    if (tid < 128)      *(float4*)&Gs[tid * 4] = *(const float4*)&lng[tid * 4];
    else                *(float4*)&Bt[(tid - 128) * 4] = *(const float4*)&lnb[(tid - 128) * 4];
    // per-row stats: each wave does 32 rows, 2 rows/iter (lane halves)
    int half = lane >> 5, l32 = lane & 31;
    for (int rr = 0; rr < 16; ++rr){
      int rloc = wave * 32 + rr * 2 + half;
      const float4* hp = (const float4*)(hA + (size_t)(m0 + rloc) * CDIM + l32 * 16);
      float4 a0 = hp[0], a1 = hp[1], a2 = hp[2], a3 = hp[3];
      float x[16] = {a0.x,a0.y,a0.z,a0.w, a1.x,a1.y,a1.z,a1.w,
                     a2.x,a2.y,a2.z,a2.w, a3.x,a3.y,a3.z,a3.w};
      float s = 0.f, q = 0.f;
      #pragma unroll
      for (int i = 0; i < 16; i++){ s += x[i]; q += x[i] * x[i]; }
      #pragma unroll
      for (int off = 1; off < 32; off <<= 1){ s += __shfl_xor(s, off); q += __shfl_xor(q, off); }
      if (l32 == 0){
        float mean = s * (1.0f / CDIM);
        float var  = q * (1.0f / CDIM) - mean * mean;
        Mu[rloc] = mean;
        Rs[rloc] = rsqrtf(var + 1e-6f);
      }
    }
    __syncthreads();
    #pragma unroll
    for (int j = 0; j < MF; j++){ mu_[j] = Mu[j * 32 + r8]; rs_[j] = Rs[j * 32 + r8]; }
  }

  auto loadA = [&](int kt, float4* r0, float4* r1){
    #pragma unroll
    for (int j = 0; j < MF; j++){
      const float* hp = hA + (size_t)(m0 + j * 32 + r8) * CDIM + kt + cb * 8;
      r0[j] = *(const float4*)hp;
      r1[j] = *(const float4*)(hp + 4);
    }
  };
  auto writeA = [&](int buf, int kt, const float4* r0, const float4* r1){
    #pragma unroll
    for (int j = 0; j < MF; j++){
      float x[8] = {r0[j].x, r0[j].y, r0[j].z, r0[j].w,
                    r1[j].x, r1[j].y, r1[j].z, r1[j].w};
      int cbase = kt + cb * 8;
      u16 w[8];
      #pragma unroll
      for (int i = 0; i < 8; i++)
        w[i] = f2bf((x[i] - mu_[j]) * rs_[j] * Gs[cbase + i] + Bt[cbase + i]);
      uint4 pk;
      pk.x = (unsigned)w[0] | ((unsigned)w[1] << 16);
      pk.y = (unsigned)w[2] | ((unsigned)w[3] << 16);
      pk.z = (unsigned)w[4] | ((unsigned)w[5] << 16);
      pk.w = (unsigned)w[6] | ((unsigned)w[7] << 16);
      *(uint4*)&As[buf][(j * 32 + r8) * 64 + ((cb ^ (r8 & 7)) << 3)] = pk;
    }
  };

  int nk = K >> 6;
  int rl = lane & 15, hg = lane >> 4;

  // prologue: stage tile 0
  stageB(0, 0);
  if constexpr (LNA){
    float4 r0[MF], r1[MF];
    loadA(0, r0, r1);
    writeA(0, 0, r0, r1);
  } else {
    stageA(0, 0);
  }
  __syncthreads();

  for (int t = 0; t < nk; ++t){
    int cur = t & 1;
    float4 r0[MF], r1[MF];
    if (t + 1 < nk){
      stageB(cur ^ 1, (t + 1) << 6);
      if constexpr (LNA) loadA((t + 1) << 6, r0, r1);
      else               stageA(cur ^ 1, (t + 1) << 6);
    }
    #pragma unroll
    for (int kk = 0; kk < 2; kk++){
      bf16x8 af[MF], bfr[NF];
      int bl = (kk << 2) + hg;
      #pragma unroll
      for (int m = 0; m < MF; m++){
        int row = wm * (BM / 2) + m * 16 + rl;
        af[m] = *(const bf16x8*)&As[cur][row * 64 + ((bl ^ (row & 7)) << 3)];
      }
      #pragma unroll
      for (int n = 0; n < NF; n++){
        int row = wn * (BN / 2) + n * 16 + rl;
        bfr[n] = *(const bf16x8*)&Bs[cur][row * 64 + ((bl ^ (row & 7)) << 3)];
      }
      #pragma unroll
      for (int m = 0; m < MF; m++)
        #pragma unroll
        for (int n = 0; n < NF; n++)
          acc[m][n] = __builtin_amdgcn_mfma_f32_16x16x32_bf16(af[m], bfr[n], acc[m][n], 0, 0, 0);
    }
    if constexpr (LNA){
      if (t + 1 < nk) writeA(cur ^ 1, (t + 1) << 6, r0, r1);
    }
    __syncthreads();
  }

  int cl = lane & 15, rg = lane >> 4;
  #pragma unroll
  for (int m = 0; m < MF; m++){
    int row0 = m0 + wm * (BM / 2) + m * 16 + rg * 4;
    #pragma unroll
    for (int n = 0; n < NF; n++){
      int col = n0 + wn * (BN / 2) + n * 16 + cl;
      float bb = bias[col];
      if (MODE == 1){
        #pragma unroll
        for (int r = 0; r < 4; r++){
          size_t idx = (size_t)(row0 + r) * N + col;
          hres[idx] += acc[m][n][r] + bb;
        }
      } else if (MODE == 2){
        #pragma unroll
        for (int r = 0; r < 4; r++){
          float x = acc[m][n][r] + bb;
          float t = 0.7978845608028654f * (x + 0.044715f * x * x * x);
          float sg = 1.0f / (1.0f + __expf(-2.0f * t));   // 0.5*(1+tanh(t)) == sigmoid(2t)
          outb[(size_t)(row0 + r) * N + col] = f2bf(x * sg);
        }
      } else {
        if (col < 1024){
          #pragma unroll
          for (int r = 0; r < 4; r++)
            outb[(size_t)(row0 + r) * N + col] = f2bf(acc[m][n][r] + bb);
        } else {
          int dh = col - 1024;
          int win = row0 >> 9, tin = row0 & 511;
          ushort4 p;
          p.x = f2bf(acc[m][n][0] + bb);
          p.y = f2bf(acc[m][n][1] + bb);
          p.z = f2bf(acc[m][n][2] + bb);
          p.w = f2bf(acc[m][n][3] + bb);
          *(ushort4*)&vT[(size_t)(win * 512 + dh) * 512 + tin] = p;
        }
      }
    }
  }
}

// ---------------- windowed flash attention: LDS-staged K/V (3-buf, counted vmcnt) -------
// 512 blocks x 4 waves; block = 64 q-rows of one (win, head); K/V tiles shared via LDS.
__global__ __launch_bounds__(256) void kt_attn(const u16* __restrict__ qkv,
                                               const u16* __restrict__ vT,
                                               u16* __restrict__ o){
  __shared__ __align__(16) u16 Ks[3][32 * 64];
  __shared__ __align__(16) u16 Vs[3][64 * 32];
  int tid = threadIdx.x, wave = tid >> 6, lane = tid & 63;
  int bx = blockIdx.x;
  int win = bx >> 6, head = (bx >> 3) & 7, q8 = bx & 7;
  int rl = lane & 15, hg = lane >> 4;
  int qbase = win * 512 + q8 * 64 + wave * 16;
  const u16* qptr  = qkv + (size_t)(qbase + rl) * QKVD + head * 64;
  const u16* kbase = qkv + (size_t)(win * 512) * QKVD + 512 + head * 64;
  const u16* vbase = vT + (size_t)(win * 512 + head * 64) * 512;

  int krow = tid >> 3;
  const u16* gK = kbase + (size_t)krow * QKVD + (((tid & 7) ^ (krow & 7)) << 3);
  int vrow = tid >> 2;
  const u16* gV = vbase + (size_t)vrow * 512 + (((tid & 3) ^ (vrow & 3)) << 3);

  auto stage = [&](int buf, int kt){
    llds16(gK + (size_t)kt * QKVD, &Ks[buf][tid * 8]);
    llds16(gV + kt, &Vs[buf][tid * 8]);
  };

  bf16x8 qf0 = *(const bf16x8*)(qptr + hg * 8);
  bf16x8 qf1 = *(const bf16x8*)(qptr + 32 + hg * 8);

  const f32x4 fzero = {0.f, 0.f, 0.f, 0.f};
  f32x4 Oa[4] = {fzero, fzero, fzero, fzero};
  float mrun = -1e30f, lrun = 0.f;

  stage(0, 0);
  stage(1, 32);
  for (int t = 0; t < 16; ++t){
    int cur = t % 3;
    if (t + 1 < 16) wait_vmcnt<2>(); else wait_vmcnt<0>();
    __builtin_amdgcn_s_barrier();
    asm volatile("" ::: "memory");
    if (t + 2 < 16) stage((t + 2) % 3, (t + 2) * 32);

    bf16x8 kf[2][2];
    #pragma unroll
    for (int c = 0; c < 2; c++)
      #pragma unroll
      for (int dk = 0; dk < 2; dk++){
        int row = c * 16 + rl;
        kf[c][dk] = *(const bf16x8*)&Ks[cur][row * 64 + ((((dk << 2) + hg) ^ (rl & 7)) << 3)];
      }
    bf16x8 vf[4];
    #pragma unroll
    for (int d = 0; d < 4; d++){
      int row = d * 16 + rl;
      vf[d] = *(const bf16x8*)&Vs[cur][row * 32 + ((hg ^ (rl & 3)) << 3)];
    }

    f32x4 s0 = fzero, s1 = fzero;
    s0 = __builtin_amdgcn_mfma_f32_16x16x32_bf16(kf[0][0], qf0, s0, 0, 0, 0);
    s0 = __builtin_amdgcn_mfma_f32_16x16x32_bf16(kf[0][1], qf1, s0, 0, 0, 0);
    s1 = __builtin_amdgcn_mfma_f32_16x16x32_bf16(kf[1][0], qf0, s1, 0, 0, 0);
    s1 = __builtin_amdgcn_mfma_f32_16x16x32_bf16(kf[1][1], qf1, s1, 0, 0, 0);
    float v[8];
    #pragma unroll
    for (int r = 0; r < 4; r++){ v[r] = s0[r] * 0.125f; v[4 + r] = s1[r] * 0.125f; }
    float tmax = v[0];
    #pragma unroll
    for (int i = 1; i < 8; i++) tmax = fmaxf(tmax, v[i]);
    tmax = fmaxf(tmax, __shfl_xor(tmax, 16));
    tmax = fmaxf(tmax, __shfl_xor(tmax, 32));
    float mnew = fmaxf(mrun, tmax);
    float corr = __expf(mrun - mnew);
    mrun = mnew;
    float p[8], ps = 0.f;
    #pragma unroll
    for (int i = 0; i < 8; i++){ p[i] = __expf(v[i] - mnew); ps += p[i]; }
    ps += __shfl_xor(ps, 16);
    ps += __shfl_xor(ps, 32);
    lrun = lrun * corr + ps;
    float c0 = __shfl(corr, (hg << 2) + 0);
    float c1 = __shfl(corr, (hg << 2) + 1);
    float c2 = __shfl(corr, (hg << 2) + 2);
    float c3 = __shfl(corr, (hg << 2) + 3);
    #pragma unroll
    for (int d = 0; d < 4; d++){
      Oa[d][0] *= c0; Oa[d][1] *= c1; Oa[d][2] *= c2; Oa[d][3] *= c3;
    }
    unsigned pk00 = pack2(p[0], p[1]);
    unsigned pk01 = pack2(p[2], p[3]);
    unsigned pk10 = pack2(p[4], p[5]);
    unsigned pk11 = pack2(p[6], p[7]);
    int idx0 = rl | ((( hg << 1)      & 3) << 4);
    int idx1 = rl | ((((hg << 1) + 1) & 3) << 4);
    bool hiC = hg >= 2;
    unsigned W0a = __shfl(pk00, idx0), W0b = __shfl(pk10, idx0);
    unsigned W1a = __shfl(pk01, idx0), W1b = __shfl(pk11, idx0);
    unsigned W2a = __shfl(pk00, idx1), W2b = __shfl(pk10, idx1);
    unsigned W3a = __shfl(pk01, idx1), W3b = __shfl(pk11, idx1);
    uint4 W;
    W.x = hiC ? W0b : W0a;
    W.y = hiC ? W1b : W1a;
    W.z = hiC ? W2b : W2a;
    W.w = hiC ? W3b : W3a;
    bf16x8 pf;
    __builtin_memcpy(&pf, &W, 16);
    #pragma unroll
    for (int d = 0; d < 4; d++)
      Oa[d] = __builtin_amdgcn_mfma_f32_16x16x32_bf16(pf, vf[d], Oa[d], 0, 0, 0);
  }

  float l0 = __shfl(lrun, (hg << 2) + 0);
  float l1 = __shfl(lrun, (hg << 2) + 1);
  float l2 = __shfl(lrun, (hg << 2) + 2);
  float l3 = __shfl(lrun, (hg << 2) + 3);
  float li[4] = {1.f / l0, 1.f / l1, 1.f / l2, 1.f / l3};
  #pragma unroll
  for (int d = 0; d < 4; d++)
    #pragma unroll
    for (int r = 0; r < 4; r++){
      int row = qbase + (hg << 2) + r;
      o[(size_t)row * CDIM + head * 64 + d * 16 + rl] = f2bf(Oa[d][r] * li[r]);
    }
}

// ---------------- final LN + head + gaussian post-process ----------------
__global__ void kt_final(const float* __restrict__ h, const float* __restrict__ w_out,
                         const float* __restrict__ b_out, const int* __restrict__ coords,
                         const float* __restrict__ offp, float* __restrict__ out){
  __shared__ float lnv[CDIM];
  __shared__ float ov[56];
  int n = blockIdx.x, lane = threadIdx.x;   // 64 threads
  const float* hr = h + (size_t)n * CDIM + lane * 8;
  float4 v0 = *(const float4*)hr, v1 = *(const float4*)(hr + 4);
  float x[8] = {v0.x, v0.y, v0.z, v0.w, v1.x, v1.y, v1.z, v1.w};
  float s = 0.f, q = 0.f;
  #pragma unroll
  for (int i = 0; i < 8; i++){ s += x[i]; q += x[i] * x[i]; }
  #pragma unroll
  for (int off = 32; off; off >>= 1){ s += __shfl_xor(s, off); q += __shfl_xor(q, off); }
  float mean = s * (1.0f / CDIM);
  float var  = q * (1.0f / CDIM) - mean * mean;
  float rr = rsqrtf(var + 1e-5f);
  #pragma unroll
  for (int i = 0; i < 8; i++) lnv[lane * 8 + i] = (x[i] - mean) * rr;
  __syncthreads();
  if (lane < 56){
    float a = b_out[lane];
    for (int k = 0; k < CDIM; k++) a += lnv[k] * w_out[k * 56 + lane];
    ov[lane] = a;
  }
  __syncthreads();
  if (lane < 12){
    int g = lane / 3, d = lane - g * 3;
    float base = ((float)coords[n * 4 + 1 + d] + 0.5f) * (1.0f / 16.0f);
    float t = tanhf(ov[lane] + offp[lane]);
    out[(size_t)n * 12 + lane] = base + t * 4.8828125e-4f;
    out[49152  + (size_t)n * 12 + lane] = ov[12 + lane];
    out[98304  + (size_t)n * 12 + lane] = ov[24 + lane];
  }
  if (lane < 16) out[147456 + (size_t)n * 16 + lane] = ov[36 + lane];
  if (lane < 4)  out[212992 + (size_t)n * 4  + lane] = ov[52 + lane];
}

extern "C" void kernel_launch(void* const* d_in, const int* in_sizes, int n_in,
                              void* d_out, int out_size, void* d_ws, size_t ws_size,
                              hipStream_t stream) {
  const float* feats = (const float*)d_in[0];
  const int*   coords = (const int*)d_in[1];
  const float* emb_x = (const float*)d_in[2];
  const float* emb_y = (const float*)d_in[3];
  const float* emb_z = (const float*)d_in[4];
  const float* w_in  = (const float*)d_in[5];
  const float* b_in  = (const float*)d_in[6];
  const float* ln1_g = (const float*)d_in[7];
  const float* ln1_b = (const float*)d_in[8];
  const float* w_qkv = (const float*)d_in[9];
  const float* b_qkv = (const float*)d_in[10];
  const float* w_o   = (const float*)d_in[11];
  const float* b_o   = (const float*)d_in[12];
  const float* ln2_g = (const float*)d_in[13];
  const float* ln2_b = (const float*)d_in[14];
  const float* w_m1  = (const float*)d_in[15];
  const float* b_m1  = (const float*)d_in[16];
  const float* w_m2  = (const float*)d_in[17];
  const float* b_m2  = (const float*)d_in[18];
  const float* w_out = (const float*)d_in[19];
  const float* b_out = (const float*)d_in[20];
  const float* offp  = (const float*)d_in[21];

  char* ws = (char*)d_ws;
  auto carve = [&](size_t bytes){ char* p = ws; ws += (bytes + 255) & ~(size_t)255; return p; };
  float* h   = (float*)carve((size_t)NTOK * CDIM * 4);
  u16* qkvb  = (u16*)carve((size_t)NTOK * QKVD * 2);
  u16* vT    = (u16*)carve((size_t)NTOK * CDIM * 2);
  u16* ob    = (u16*)carve((size_t)NTOK * CDIM * 2);
  u16* ub    = (u16*)carve((size_t)NTOK * MLPD * 2);
  u16* wqkvT = (u16*)carve((size_t)LAYERS * QKVD * CDIM * 2);
  u16* woT   = (u16*)carve((size_t)LAYERS * CDIM * CDIM * 2);
  u16* wm1T  = (u16*)carve((size_t)LAYERS * MLPD * CDIM * 2);
  u16* wm2T  = (u16*)carve((size_t)LAYERS * CDIM * MLPD * 2);

  kt_transpose<<<dim3(QKVD/32, CDIM/32, LAYERS), 256, 0, stream>>>(w_qkv, wqkvT, CDIM, QKVD);
  kt_transpose<<<dim3(CDIM/32, CDIM/32, LAYERS), 256, 0, stream>>>(w_o,   woT,   CDIM, CDIM);
  kt_transpose<<<dim3(MLPD/32, CDIM/32, LAYERS), 256, 0, stream>>>(w_m1,  wm1T,  CDIM, MLPD);
  kt_transpose<<<dim3(CDIM/32, MLPD/32, LAYERS), 256, 0, stream>>>(w_m2,  wm2T,  MLPD, CDIM);
  kt_embed<<<NTOK, 256, 0, stream>>>(feats, coords, emb_x, emb_y, emb_z, w_in, b_in, h);

  for (int l = 0; l < LAYERS; ++l){
    kt_gemm<128,128,0,true><<<(NTOK/128)*(QKVD/128), 256, 0, stream>>>(
        nullptr, h, ln1_g + l*CDIM, ln1_b + l*CDIM,
        wqkvT + (size_t)l*QKVD*CDIM, b_qkv + l*QKVD, qkvb, nullptr, vT, QKVD, CDIM);
    kt_attn<<<512, 256, 0, stream>>>(qkvb, vT, ob);
    kt_gemm<64,64,1,false><<<(NTOK/64)*(CDIM/64), 256, 0, stream>>>(
        ob, nullptr, nullptr, nullptr,
        woT + (size_t)l*CDIM*CDIM, b_o + l*CDIM, nullptr, h, nullptr, CDIM, CDIM);
    kt_gemm<128,128,2,true><<<(NTOK/128)*(MLPD/128), 256, 0, stream>>>(
        nullptr, h, ln2_g + l*CDIM, ln2_b + l*CDIM,
        wm1T + (size_t)l*MLPD*CDIM, b_m1 + l*MLPD, ub, nullptr, nullptr, MLPD, CDIM);
    kt_gemm<64,64,1,false><<<(NTOK/64)*(CDIM/64), 256, 0, stream>>>(
        ub, nullptr, nullptr, nullptr,
        wm2T + (size_t)l*CDIM*MLPD, b_m2 + l*CDIM, nullptr, h, nullptr, CDIM, MLPD);
  }
  kt_final<<<NTOK, 64, 0, stream>>>(h, w_out, b_out, coords, offp, (float*)d_out);
}

// Round 9
// 848.373 us; speedup vs baseline: 1.2456x; 1.2456x over previous
//
#include <hip/hip_runtime.h>
#include <stdint.h>

typedef unsigned short u16;
typedef short bf16x8 __attribute__((ext_vector_type(8)));
typedef float f32x4 __attribute__((ext_vector_type(4)));

#define NTOK 4096
#define CDIM 512
#define NHEAD 8
#define LAYERS 8
#define MLPD 2048
#define QKVD 1536

__device__ __forceinline__ u16 f2bf(float f){
  union { float f; unsigned u; } c; c.f = f;
  return (u16)((c.u + 0x7FFFu + ((c.u >> 16) & 1u)) >> 16);
}

__device__ __forceinline__ unsigned pack2(float a, float b){
  return (unsigned)f2bf(a) | ((unsigned)f2bf(b) << 16);
}

__device__ __forceinline__ void llds16(const void* g, void* l){
  __builtin_amdgcn_global_load_lds((const __attribute__((address_space(1))) void*)g,
                                   (__attribute__((address_space(3))) void*)l, 16, 0, 0);
}

template<int N> __device__ __forceinline__ void wait_vmcnt(){
  if constexpr (N == 0) asm volatile("s_waitcnt vmcnt(0)" ::: "memory");
  else if constexpr (N == 2) asm volatile("s_waitcnt vmcnt(2)" ::: "memory");
  else if constexpr (N == 4) asm volatile("s_waitcnt vmcnt(4)" ::: "memory");
  else static_assert(N == 0 || N == 2 || N == 4, "unsupported vmcnt");
}

// ------------- merged weight transpose+convert: W[K][N] fp32 -> Wt[N][K] bf16 -----------
// seg0 qkv 512x1536 x8 | seg1 o 512x512 x8 | seg2 m1 512x2048 x8 | seg3 m2 2048x512 x8
// seg4 w_out 512x56 -> padded [64][512] (cols >=56 zeroed)
__global__ void kt_transpose_all(const float* __restrict__ wqkv, const float* __restrict__ wo,
                                 const float* __restrict__ wm1, const float* __restrict__ wm2,
                                 const float* __restrict__ wout,
                                 u16* __restrict__ qkvT, u16* __restrict__ oT,
                                 u16* __restrict__ m1T, u16* __restrict__ m2T,
                                 u16* __restrict__ outT){
  __shared__ float tile[32][33];
  int bid = blockIdx.x;
  const float* W; u16* Wt; int K, N, k0, n0; bool guard = false;
  if (bid < 6144){            // qkv: 48x16 tiles/layer
    int l = bid / 768, r = bid % 768;
    W = wqkv + (size_t)l * 512 * 1536; Wt = qkvT + (size_t)l * 512 * 1536;
    K = 512; N = 1536; n0 = (r % 48) * 32; k0 = (r / 48) * 32;
  } else if (bid < 8192){     // o: 16x16
    int b = bid - 6144; int l = b / 256, r = b % 256;
    W = wo + (size_t)l * 512 * 512; Wt = oT + (size_t)l * 512 * 512;
    K = 512; N = 512; n0 = (r % 16) * 32; k0 = (r / 16) * 32;
  } else if (bid < 16384){    // m1: 64x16
    int b = bid - 8192; int l = b / 1024, r = b % 1024;
    W = wm1 + (size_t)l * 512 * 2048; Wt = m1T + (size_t)l * 512 * 2048;
    K = 512; N = 2048; n0 = (r % 64) * 32; k0 = (r / 64) * 32;
  } else if (bid < 24576){    // m2: 16x64
    int b = bid - 16384; int l = b / 1024, r = b % 1024;
    W = wm2 + (size_t)l * 2048 * 512; Wt = m2T + (size_t)l * 2048 * 512;
    K = 2048; N = 512; n0 = (r % 16) * 32; k0 = (r / 16) * 32;
  } else {                    // w_out: 2x16, N=56 guarded, out stride 512
    int r = bid - 24576;
    W = wout; Wt = outT;
    K = 512; N = 56; n0 = (r % 2) * 32; k0 = (r / 2) * 32;
    guard = true;
  }
  int t = threadIdx.x;
  int r = t >> 3, c4 = (t & 7) << 2;
  if (guard){
    #pragma unroll
    for (int i = 0; i < 4; i++){
      int col = n0 + c4 + i;
      tile[r][c4 + i] = (col < N) ? W[(size_t)(k0 + r) * N + col] : 0.f;
    }
  } else {
    float4 v = *(const float4*)&W[(size_t)(k0 + r) * N + n0 + c4];
    tile[r][c4 + 0] = v.x; tile[r][c4 + 1] = v.y; tile[r][c4 + 2] = v.z; tile[r][c4 + 3] = v.w;
  }
  __syncthreads();
  ushort4 o;
  o.x = f2bf(tile[c4 + 0][r]);
  o.y = f2bf(tile[c4 + 1][r]);
  o.z = f2bf(tile[c4 + 2][r]);
  o.w = f2bf(tile[c4 + 3][r]);
  *(ushort4*)&Wt[(size_t)(n0 + r) * K + k0 + c4] = o;
}

// ---------------- embed: h = feats@w_in + b_in + pos-emb ----------------
__global__ void kt_embed(const float* __restrict__ feats, const int* __restrict__ coords,
                         const float* __restrict__ ex, const float* __restrict__ ey,
                         const float* __restrict__ ez, const float* __restrict__ w_in,
                         const float* __restrict__ b_in, float* __restrict__ h){
  __shared__ float fs[8];
  __shared__ int cc[3];
  int n = blockIdx.x, t = threadIdx.x;
  if (t < 8) fs[t] = feats[n * 8 + t];
  if (t == 8) { cc[0] = coords[n*4+1]; cc[1] = coords[n*4+2]; cc[2] = coords[n*4+3]; }
  __syncthreads();
  for (int c = t; c < CDIM; c += 256){
    float acc = b_in[c];
    #pragma unroll
    for (int i = 0; i < 8; i++) acc += fs[i] * w_in[i * CDIM + c];
    float pe;
    if (c < 170)      pe = ex[cc[0] * 170 + c];
    else if (c < 340) pe = ey[cc[1] * 170 + (c - 170)];
    else              pe = ez[cc[2] * 172 + (c - 340)];
    h[(size_t)n * CDIM + c] = acc + pe;
  }
}

// ---------------- LayerNorm: fp32 h -> bf16 out ----------------
__global__ void kt_ln(const float* __restrict__ h, const float* __restrict__ g,
                      const float* __restrict__ b, u16* __restrict__ out, float eps){
  int wave = threadIdx.x >> 6, lane = threadIdx.x & 63;
  int row = blockIdx.x * 4 + wave;
  const float* hr = h + (size_t)row * CDIM + lane * 8;
  float4 v0 = *(const float4*)hr, v1 = *(const float4*)(hr + 4);
  float x[8] = {v0.x, v0.y, v0.z, v0.w, v1.x, v1.y, v1.z, v1.w};
  float s = 0.f, q = 0.f;
  #pragma unroll
  for (int i = 0; i < 8; i++){ s += x[i]; q += x[i] * x[i]; }
  #pragma unroll
  for (int off = 32; off; off >>= 1){ s += __shfl_xor(s, off); q += __shfl_xor(q, off); }
  float mean = s * (1.0f / CDIM);
  float var  = q * (1.0f / CDIM) - mean * mean;
  float rr = rsqrtf(var + eps);
  int cb = lane * 8;
  u16 u[8];
  #pragma unroll
  for (int i = 0; i < 8; i++)
    u[i] = f2bf((x[i] - mean) * rr * g[cb + i] + b[cb + i]);
  uint4 pk;
  pk.x = (unsigned)u[0] | ((unsigned)u[1] << 16);
  pk.y = (unsigned)u[2] | ((unsigned)u[3] << 16);
  pk.z = (unsigned)u[4] | ((unsigned)u[5] << 16);
  pk.w = (unsigned)u[6] | ((unsigned)u[7] << 16);
  *(uint4*)&out[(size_t)row * CDIM + cb] = pk;
}

// ---------------- bf16 GEMM: C[M=4096][N] = A[M][K] @ Wt[N][K]^T + bias ----------------
// 2-buffer, one __syncthreads per K-step. 4 waves; wave tile (BM/2)x(BN/2).
// XCD-chunked 1D grid swizzle (blocks on one XCD share A-panels; fits 4MB L2).
template<int BM, int BN, int MODE>
__global__ __launch_bounds__(256) void kt_gemm(
    const u16* __restrict__ A, const u16* __restrict__ Wt, const float* __restrict__ bias,
    u16* __restrict__ outb, float* __restrict__ hres, u16* __restrict__ vT, int N, int K)
{
  constexpr int MF = BM / 32;
  constexpr int NF = BN / 32;
  constexpr int Mt = NTOK / BM;
  constexpr int Mx = Mt / 8;
  __shared__ __align__(16) u16 As[2][BM * 64];
  __shared__ __align__(16) u16 Bs[2][BN * 64];
  int tid = threadIdx.x, wave = tid >> 6, lane = tid & 63;

  int Nt = N / BN;
  int bid = blockIdx.x;
  int xcd = bid & 7, slot = bid >> 3;
  int miL = slot / Nt;
  int ni = slot - miL * Nt;
  int m0 = (xcd * Mx + miL) * BM, n0 = ni * BN;

  int wm = wave >> 1, wn = wave & 1;
  f32x4 acc[MF][NF];
  const f32x4 fzero = {0.f, 0.f, 0.f, 0.f};
  #pragma unroll
  for (int m = 0; m < MF; m++)
    #pragma unroll
    for (int n = 0; n < NF; n++) acc[m][n] = fzero;

  int srow = lane >> 3;
  int sblk = (lane & 7) ^ srow;
  const u16* gA = A  + (size_t)(m0 + wave * 8 + srow) * K + sblk * 8;
  const u16* gB = Wt + (size_t)(n0 + wave * 8 + srow) * K + sblk * 8;

  auto stage = [&](int buf, int kt){
    #pragma unroll
    for (int j = 0; j < MF; j++)
      llds16(gA + (size_t)(j * 32) * K + kt, &As[buf][(j * 32 + wave * 8) * 64]);
    #pragma unroll
    for (int j = 0; j < NF; j++)
      llds16(gB + (size_t)(j * 32) * K + kt, &Bs[buf][(j * 32 + wave * 8) * 64]);
  };

  int nk = K >> 6;
  stage(0, 0);
  __syncthreads();
  int rl = lane & 15, hg = lane >> 4;
  for (int t = 0; t < nk; ++t){
    int cur = t & 1;
    if (t + 1 < nk) stage(cur ^ 1, (t + 1) << 6);
    #pragma unroll
    for (int kk = 0; kk < 2; kk++){
      bf16x8 af[MF], bfr[NF];
      int bl = (kk << 2) + hg;
      #pragma unroll
      for (int m = 0; m < MF; m++){
        int row = wm * (BM / 2) + m * 16 + rl;
        af[m] = *(const bf16x8*)&As[cur][row * 64 + ((bl ^ (row & 7)) << 3)];
      }
      #pragma unroll
      for (int n = 0; n < NF; n++){
        int row = wn * (BN / 2) + n * 16 + rl;
        bfr[n] = *(const bf16x8*)&Bs[cur][row * 64 + ((bl ^ (row & 7)) << 3)];
      }
      #pragma unroll
      for (int m = 0; m < MF; m++)
        #pragma unroll
        for (int n = 0; n < NF; n++)
          acc[m][n] = __builtin_amdgcn_mfma_f32_16x16x32_bf16(af[m], bfr[n], acc[m][n], 0, 0, 0);
    }
    __syncthreads();
  }

  int cl = lane & 15, rg = lane >> 4;
  #pragma unroll
  for (int m = 0; m < MF; m++){
    int row0 = m0 + wm * (BM / 2) + m * 16 + rg * 4;
    #pragma unroll
    for (int n = 0; n < NF; n++){
      int col = n0 + wn * (BN / 2) + n * 16 + cl;
      float bb = bias[col];
      if (MODE == 1){
        #pragma unroll
        for (int r = 0; r < 4; r++){
          size_t idx = (size_t)(row0 + r) * N + col;
          hres[idx] += acc[m][n][r] + bb;
        }
      } else if (MODE == 2){
        #pragma unroll
        for (int r = 0; r < 4; r++){
          float x = acc[m][n][r] + bb;
          float t = 0.7978845608028654f * (x + 0.044715f * x * x * x);
          float sg = 1.0f / (1.0f + __expf(-2.0f * t));   // 0.5*(1+tanh(t)) == sigmoid(2t)
          outb[(size_t)(row0 + r) * N + col] = f2bf(x * sg);
        }
      } else {
        if (col < 1024){
          #pragma unroll
          for (int r = 0; r < 4; r++)
            outb[(size_t)(row0 + r) * N + col] = f2bf(acc[m][n][r] + bb);
        } else {
          int dh = col - 1024;
          int win = row0 >> 9, tin = row0 & 511;
          ushort4 p;
          p.x = f2bf(acc[m][n][0] + bb);
          p.y = f2bf(acc[m][n][1] + bb);
          p.z = f2bf(acc[m][n][2] + bb);
          p.w = f2bf(acc[m][n][3] + bb);
          *(ushort4*)&vT[(size_t)(win * 512 + dh) * 512 + tin] = p;
        }
      }
    }
  }
}

// ---------------- windowed flash attention: LDS-staged K/V (3-buf, counted vmcnt) -------
// 512 blocks x 4 waves; block = 64 q-rows of one (win, head); K/V tiles shared via LDS.
__global__ __launch_bounds__(256) void kt_attn(const u16* __restrict__ qkv,
                                               const u16* __restrict__ vT,
                                               u16* __restrict__ o){
  __shared__ __align__(16) u16 Ks[3][32 * 64];
  __shared__ __align__(16) u16 Vs[3][64 * 32];
  int tid = threadIdx.x, wave = tid >> 6, lane = tid & 63;
  int bx = blockIdx.x;
  int win = bx >> 6, head = (bx >> 3) & 7, q8 = bx & 7;
  int rl = lane & 15, hg = lane >> 4;
  int qbase = win * 512 + q8 * 64 + wave * 16;
  const u16* qptr  = qkv + (size_t)(qbase + rl) * QKVD + head * 64;
  const u16* kbase = qkv + (size_t)(win * 512) * QKVD + 512 + head * 64;
  const u16* vbase = vT + (size_t)(win * 512 + head * 64) * 512;

  int krow = tid >> 3;
  const u16* gK = kbase + (size_t)krow * QKVD + (((tid & 7) ^ (krow & 7)) << 3);
  int vrow = tid >> 2;
  const u16* gV = vbase + (size_t)vrow * 512 + (((tid & 3) ^ (vrow & 3)) << 3);

  auto stage = [&](int buf, int kt){
    llds16(gK + (size_t)kt * QKVD, &Ks[buf][tid * 8]);
    llds16(gV + kt, &Vs[buf][tid * 8]);
  };

  bf16x8 qf0 = *(const bf16x8*)(qptr + hg * 8);
  bf16x8 qf1 = *(const bf16x8*)(qptr + 32 + hg * 8);

  const f32x4 fzero = {0.f, 0.f, 0.f, 0.f};
  f32x4 Oa[4] = {fzero, fzero, fzero, fzero};
  float mrun = -1e30f, lrun = 0.f;

  stage(0, 0);
  stage(1, 32);
  for (int t = 0; t < 16; ++t){
    int cur = t % 3;
    if (t + 1 < 16) wait_vmcnt<2>(); else wait_vmcnt<0>();
    __builtin_amdgcn_s_barrier();
    asm volatile("" ::: "memory");
    if (t + 2 < 16) stage((t + 2) % 3, (t + 2) * 32);

    bf16x8 kf[2][2];
    #pragma unroll
    for (int c = 0; c < 2; c++)
      #pragma unroll
      for (int dk = 0; dk < 2; dk++){
        int row = c * 16 + rl;
        kf[c][dk] = *(const bf16x8*)&Ks[cur][row * 64 + ((((dk << 2) + hg) ^ (rl & 7)) << 3)];
      }
    bf16x8 vf[4];
    #pragma unroll
    for (int d = 0; d < 4; d++){
      int row = d * 16 + rl;
      vf[d] = *(const bf16x8*)&Vs[cur][row * 32 + ((hg ^ (rl & 3)) << 3)];
    }

    f32x4 s0 = fzero, s1 = fzero;
    s0 = __builtin_amdgcn_mfma_f32_16x16x32_bf16(kf[0][0], qf0, s0, 0, 0, 0);
    s0 = __builtin_amdgcn_mfma_f32_16x16x32_bf16(kf[0][1], qf1, s0, 0, 0, 0);
    s1 = __builtin_amdgcn_mfma_f32_16x16x32_bf16(kf[1][0], qf0, s1, 0, 0, 0);
    s1 = __builtin_amdgcn_mfma_f32_16x16x32_bf16(kf[1][1], qf1, s1, 0, 0, 0);
    float v[8];
    #pragma unroll
    for (int r = 0; r < 4; r++){ v[r] = s0[r] * 0.125f; v[4 + r] = s1[r] * 0.125f; }
    float tmax = v[0];
    #pragma unroll
    for (int i = 1; i < 8; i++) tmax = fmaxf(tmax, v[i]);
    tmax = fmaxf(tmax, __shfl_xor(tmax, 16));
    tmax = fmaxf(tmax, __shfl_xor(tmax, 32));
    float mnew = fmaxf(mrun, tmax);
    float corr = __expf(mrun - mnew);
    mrun = mnew;
    float p[8], ps = 0.f;
    #pragma unroll
    for (int i = 0; i < 8; i++){ p[i] = __expf(v[i] - mnew); ps += p[i]; }
    ps += __shfl_xor(ps, 16);
    ps += __shfl_xor(ps, 32);
    lrun = lrun * corr + ps;
    float c0 = __shfl(corr, (hg << 2) + 0);
    float c1 = __shfl(corr, (hg << 2) + 1);
    float c2 = __shfl(corr, (hg << 2) + 2);
    float c3 = __shfl(corr, (hg << 2) + 3);
    #pragma unroll
    for (int d = 0; d < 4; d++){
      Oa[d][0] *= c0; Oa[d][1] *= c1; Oa[d][2] *= c2; Oa[d][3] *= c3;
    }
    unsigned pk00 = pack2(p[0], p[1]);
    unsigned pk01 = pack2(p[2], p[3]);
    unsigned pk10 = pack2(p[4], p[5]);
    unsigned pk11 = pack2(p[6], p[7]);
    int idx0 = rl | ((( hg << 1)      & 3) << 4);
    int idx1 = rl | ((((hg << 1) + 1) & 3) << 4);
    bool hiC = hg >= 2;
    unsigned W0a = __shfl(pk00, idx0), W0b = __shfl(pk10, idx0);
    unsigned W1a = __shfl(pk01, idx0), W1b = __shfl(pk11, idx0);
    unsigned W2a = __shfl(pk00, idx1), W2b = __shfl(pk10, idx1);
    unsigned W3a = __shfl(pk01, idx1), W3b = __shfl(pk11, idx1);
    uint4 W;
    W.x = hiC ? W0b : W0a;
    W.y = hiC ? W1b : W1a;
    W.z = hiC ? W2b : W2a;
    W.w = hiC ? W3b : W3a;
    bf16x8 pf;
    __builtin_memcpy(&pf, &W, 16);
    #pragma unroll
    for (int d = 0; d < 4; d++)
      Oa[d] = __builtin_amdgcn_mfma_f32_16x16x32_bf16(pf, vf[d], Oa[d], 0, 0, 0);
  }

  float l0 = __shfl(lrun, (hg << 2) + 0);
  float l1 = __shfl(lrun, (hg << 2) + 1);
  float l2 = __shfl(lrun, (hg << 2) + 2);
  float l3 = __shfl(lrun, (hg << 2) + 3);
  float li[4] = {1.f / l0, 1.f / l1, 1.f / l2, 1.f / l3};
  #pragma unroll
  for (int d = 0; d < 4; d++)
    #pragma unroll
    for (int r = 0; r < 4; r++){
      int row = qbase + (hg << 2) + r;
      o[(size_t)row * CDIM + head * 64 + d * 16 + rl] = f2bf(Oa[d][r] * li[r]);
    }
}

// ------------- final: fused LN(eps 1e-5) + head GEMM (N=56 pad 64) + post-process -------
// 64 blocks x 4 waves; block owns 64 full rows -> LN stats computed once (no redundancy).
__global__ __launch_bounds__(256) void kt_final(const float* __restrict__ h,
                                                const u16* __restrict__ WoT,
                                                const float* __restrict__ b_out,
                                                const int* __restrict__ coords,
                                                const float* __restrict__ offp,
                                                float* __restrict__ out){
  __shared__ __align__(16) u16 As[2][64 * 64];
  __shared__ __align__(16) u16 Bs[2][64 * 64];
  __shared__ float Mu[64], Rs[64];
  int tid = threadIdx.x, wave = tid >> 6, lane = tid & 63;
  int m0 = blockIdx.x * 64;
  int wm = wave >> 1, wn = wave & 1;

  // per-row LN stats (each wave: 16 rows)
  for (int rr = 0; rr < 16; ++rr){
    int rloc = wave * 16 + rr;
    const float* hp = h + (size_t)(m0 + rloc) * CDIM + lane * 8;
    float4 v0 = *(const float4*)hp, v1 = *(const float4*)(hp + 4);
    float x[8] = {v0.x, v0.y, v0.z, v0.w, v1.x, v1.y, v1.z, v1.w};
    float s = 0.f, q = 0.f;
    #pragma unroll
    for (int i = 0; i < 8; i++){ s += x[i]; q += x[i] * x[i]; }
    #pragma unroll
    for (int off = 32; off; off >>= 1){ s += __shfl_xor(s, off); q += __shfl_xor(q, off); }
    if (lane == 0){
      float mean = s * (1.0f / CDIM);
      float var  = q * (1.0f / CDIM) - mean * mean;
      Mu[rloc] = mean;
      Rs[rloc] = rsqrtf(var + 1e-5f);
    }
  }
  __syncthreads();

  int ar = tid >> 2, ac = tid & 3;   // A-staging: row 0..63, two 8-col blocks
  float mu_ = Mu[ar], rs_ = Rs[ar];

  auto stageA = [&](int buf, int kt){
    const float* hp = h + (size_t)(m0 + ar) * CDIM + kt + ac * 16;
    float4 a0 = *(const float4*)hp, a1 = *(const float4*)(hp + 4);
    float4 a2 = *(const float4*)(hp + 8), a3 = *(const float4*)(hp + 12);
    float x[16] = {a0.x,a0.y,a0.z,a0.w, a1.x,a1.y,a1.z,a1.w,
                   a2.x,a2.y,a2.z,a2.w, a3.x,a3.y,a3.z,a3.w};
    u16 w[16];
    #pragma unroll
    for (int i = 0; i < 16; i++) w[i] = f2bf((x[i] - mu_) * rs_);
    uint4 p0, p1;
    p0.x = (unsigned)w[0] | ((unsigned)w[1] << 16);
    p0.y = (unsigned)w[2] | ((unsigned)w[3] << 16);
    p0.z = (unsigned)w[4] | ((unsigned)w[5] << 16);
    p0.w = (unsigned)w[6] | ((unsigned)w[7] << 16);
    p1.x = (unsigned)w[8] | ((unsigned)w[9] << 16);
    p1.y = (unsigned)w[10] | ((unsigned)w[11] << 16);
    p1.z = (unsigned)w[12] | ((unsigned)w[13] << 16);
    p1.w = (unsigned)w[14] | ((unsigned)w[15] << 16);
    int j0 = ac * 2, j1 = ac * 2 + 1;
    *(uint4*)&As[buf][ar * 64 + ((j0 ^ (ar & 7)) << 3)] = p0;
    *(uint4*)&As[buf][ar * 64 + ((j1 ^ (ar & 7)) << 3)] = p1;
  };

  int srow = lane >> 3;
  int sblk = (lane & 7) ^ srow;
  const u16* gB = WoT + (size_t)(wave * 8 + srow) * CDIM + sblk * 8;
  auto stageB = [&](int buf, int kt){
    #pragma unroll
    for (int j = 0; j < 2; j++)
      llds16(gB + (size_t)(j * 32) * CDIM + kt, &Bs[buf][(j * 32 + wave * 8) * 64]);
  };

  f32x4 acc[2][2];
  const f32x4 fzero = {0.f, 0.f, 0.f, 0.f};
  acc[0][0] = fzero; acc[0][1] = fzero; acc[1][0] = fzero; acc[1][1] = fzero;

  stageB(0, 0);
  stageA(0, 0);
  __syncthreads();
  int rl = lane & 15, hg = lane >> 4;
  for (int t = 0; t < 8; ++t){
    int cur = t & 1;
    if (t + 1 < 8){
      stageB(cur ^ 1, (t + 1) << 6);
      stageA(cur ^ 1, (t + 1) << 6);
    }
    #pragma unroll
    for (int kk = 0; kk < 2; kk++){
      bf16x8 af[2], bfr[2];
      int bl = (kk << 2) + hg;
      #pragma unroll
      for (int m = 0; m < 2; m++){
        int row = wm * 32 + m * 16 + rl;
        af[m] = *(const bf16x8*)&As[cur][row * 64 + ((bl ^ (row & 7)) << 3)];
      }
      #pragma unroll
      for (int n = 0; n < 2; n++){
        int row = wn * 32 + n * 16 + rl;
        bfr[n] = *(const bf16x8*)&Bs[cur][row * 64 + ((bl ^ (row & 7)) << 3)];
      }
      #pragma unroll
      for (int m = 0; m < 2; m++)
        #pragma unroll
        for (int n = 0; n < 2; n++)
          acc[m][n] = __builtin_amdgcn_mfma_f32_16x16x32_bf16(af[m], bfr[n], acc[m][n], 0, 0, 0);
    }
    __syncthreads();
  }

  int cl = lane & 15, rg = lane >> 4;
  #pragma unroll
  for (int m = 0; m < 2; m++){
    int row0 = m0 + wm * 32 + m * 16 + rg * 4;
    #pragma unroll
    for (int n = 0; n < 2; n++){
      int col = wn * 32 + n * 16 + cl;
      if (col < 56){
        float bb = b_out[col];
        #pragma unroll
        for (int r = 0; r < 4; r++){
          int row = row0 + r;
          float v = acc[m][n][r] + bb;
          if (col < 12){
            int d = col - (col / 3) * 3;
            float base = ((float)coords[row * 4 + 1 + d] + 0.5f) * (1.0f / 16.0f);
            float tt = tanhf(v + offp[col]);
            out[(size_t)row * 12 + col] = base + tt * 4.8828125e-4f;
          } else if (col < 24){
            out[49152 + (size_t)row * 12 + (col - 12)] = v;
          } else if (col < 36){
            out[98304 + (size_t)row * 12 + (col - 24)] = v;
          } else if (col < 52){
            out[147456 + (size_t)row * 16 + (col - 36)] = v;
          } else {
            out[212992 + (size_t)row * 4 + (col - 52)] = v;
          }
        }
      }
    }
  }
}

extern "C" void kernel_launch(void* const* d_in, const int* in_sizes, int n_in,
                              void* d_out, int out_size, void* d_ws, size_t ws_size,
                              hipStream_t stream) {
  const float* feats = (const float*)d_in[0];
  const int*   coords = (const int*)d_in[1];
  const float* emb_x = (const float*)d_in[2];
  const float* emb_y = (const float*)d_in[3];
  const float* emb_z = (const float*)d_in[4];
  const float* w_in  = (const float*)d_in[5];
  const float* b_in  = (const float*)d_in[6];
  const float* ln1_g = (const float*)d_in[7];
  const float* ln1_b = (const float*)d_in[8];
  const float* w_qkv = (const float*)d_in[9];
  const float* b_qkv = (const float*)d_in[10];
  const float* w_o   = (const float*)d_in[11];
  const float* b_o   = (const float*)d_in[12];
  const float* ln2_g = (const float*)d_in[13];
  const float* ln2_b = (const float*)d_in[14];
  const float* w_m1  = (const float*)d_in[15];
  const float* b_m1  = (const float*)d_in[16];
  const float* w_m2  = (const float*)d_in[17];
  const float* b_m2  = (const float*)d_in[18];
  const float* w_out = (const float*)d_in[19];
  const float* b_out = (const float*)d_in[20];
  const float* offp  = (const float*)d_in[21];

  char* ws = (char*)d_ws;
  auto carve = [&](size_t bytes){ char* p = ws; ws += (bytes + 255) & ~(size_t)255; return p; };
  float* h   = (float*)carve((size_t)NTOK * CDIM * 4);
  u16* a     = (u16*)carve((size_t)NTOK * CDIM * 2);
  u16* qkvb  = (u16*)carve((size_t)NTOK * QKVD * 2);
  u16* vT    = (u16*)carve((size_t)NTOK * CDIM * 2);
  u16* ob    = (u16*)carve((size_t)NTOK * CDIM * 2);
  u16* ub    = (u16*)carve((size_t)NTOK * MLPD * 2);
  u16* wqkvT = (u16*)carve((size_t)LAYERS * QKVD * CDIM * 2);
  u16* woT   = (u16*)carve((size_t)LAYERS * CDIM * CDIM * 2);
  u16* wm1T  = (u16*)carve((size_t)LAYERS * MLPD * CDIM * 2);
  u16* wm2T  = (u16*)carve((size_t)LAYERS * CDIM * MLPD * 2);
  u16* woutT = (u16*)carve((size_t)64 * CDIM * 2);

  kt_transpose_all<<<24608, 256, 0, stream>>>(w_qkv, w_o, w_m1, w_m2, w_out,
                                              wqkvT, woT, wm1T, wm2T, woutT);
  kt_embed<<<NTOK, 256, 0, stream>>>(feats, coords, emb_x, emb_y, emb_z, w_in, b_in, h);

  for (int l = 0; l < LAYERS; ++l){
    kt_ln<<<NTOK/4, 256, 0, stream>>>(h, ln1_g + l*CDIM, ln1_b + l*CDIM, a, 1e-6f);
    kt_gemm<128,128,0><<<(NTOK/128)*(QKVD/128), 256, 0, stream>>>(
        a, wqkvT + (size_t)l*QKVD*CDIM, b_qkv + l*QKVD, qkvb, nullptr, vT, QKVD, CDIM);
    kt_attn<<<512, 256, 0, stream>>>(qkvb, vT, ob);
    kt_gemm<64,64,1><<<(NTOK/64)*(CDIM/64), 256, 0, stream>>>(
        ob, woT + (size_t)l*CDIM*CDIM, b_o + l*CDIM, nullptr, h, nullptr, CDIM, CDIM);
    kt_ln<<<NTOK/4, 256, 0, stream>>>(h, ln2_g + l*CDIM, ln2_b + l*CDIM, a, 1e-6f);
    kt_gemm<128,128,2><<<(NTOK/128)*(MLPD/128), 256, 0, stream>>>(
        a, wm1T + (size_t)l*MLPD*CDIM, b_m1 + l*MLPD, ub, nullptr, nullptr, MLPD, CDIM);
    kt_gemm<64,64,1><<<(NTOK/64)*(CDIM/64), 256, 0, stream>>>(
        ub, wm2T + (size_t)l*CDIM*MLPD, b_m2 + l*CDIM, nullptr, h, nullptr, CDIM, MLPD);
  }
  kt_final<<<64, 256, 0, stream>>>(h, woutT, b_out, coords, offp, (float*)d_out);
}